// Round 16
// baseline (480.055 us; speedup 1.0000x reference)
//
#include <hip/hip_runtime.h>
#include <hip/hip_bf16.h>

#define T_SEQ 1024
#define NH 8
#define DH 512
#define HK 4096

typedef __attribute__((ext_vector_type(8))) __bf16 bf16x8;
typedef __attribute__((ext_vector_type(4))) float f32x4;

#define QK_SCALE 0.21022410381342863f           // 512^-0.25
#define QK_SCALE_LOG2E 0.30328926584f           // QK_SCALE * log2(e): Q side -> exp2 domain

static __device__ __forceinline__ unsigned short f2bu(float f) {
  union { __hip_bfloat16 h; unsigned short u; } cv;
  cv.h = __float2bfloat16(f);
  return cv.u;
}

#define GLOAD_LDS16(gsrc, ldst) \
  __builtin_amdgcn_global_load_lds((const __attribute__((address_space(1))) void*)(gsrc), \
                                   (__attribute__((address_space(3))) void*)(ldst), 16, 0, 0)

// ---------------- convert / transpose ----------------
__global__ void cvt_bf16_kernel(const float* __restrict__ in, unsigned short* __restrict__ out, int n4) {
  int i = blockIdx.x * blockDim.x + threadIdx.x;
  if (i >= n4) return;
  const float4 v = reinterpret_cast<const float4*>(in)[i];
  ushort4 u; u.x = f2bu(v.x); u.y = f2bu(v.y); u.z = f2bu(v.z); u.w = f2bu(v.w);
  reinterpret_cast<ushort4*>(out)[i] = u;
}

// out[C][R] = bf16(in[R][C])
__global__ void transpose_cvt_kernel(const float* __restrict__ in, unsigned short* __restrict__ out,
                                     int R, int C) {
  __shared__ float tile[32][33];
  const int c0 = blockIdx.x * 32, r0 = blockIdx.y * 32;
  const int tx = threadIdx.x, ty = threadIdx.y;
  #pragma unroll
  for (int i = ty; i < 32; i += 8)
    tile[i][tx] = in[(size_t)(r0 + i) * C + (c0 + tx)];
  __syncthreads();
  #pragma unroll
  for (int i = ty; i < 32; i += 8)
    out[(size_t)(c0 + i) * R + (r0 + tx)] = f2bu(tile[tx][i]);
}

// fused: transposes Wq/Wk/Wv (each [512][4096]) into Wcat [12288][512], z selects source.
__global__ void transpose_cvt3_kernel(const float* __restrict__ Wq, const float* __restrict__ Wk,
                                      const float* __restrict__ Wv, unsigned short* __restrict__ out) {
  __shared__ float tile[32][33];
  const float* in = (blockIdx.z == 0) ? Wq : (blockIdx.z == 1) ? Wk : Wv;
  unsigned short* dst = out + (size_t)blockIdx.z * 4096 * 512;
  const int c0 = blockIdx.x * 32, r0 = blockIdx.y * 32;
  const int tx = threadIdx.x, ty = threadIdx.y;
  #pragma unroll
  for (int i = ty; i < 32; i += 8)
    tile[i][tx] = in[(size_t)(r0 + i) * 4096 + (c0 + tx)];
  __syncthreads();
  #pragma unroll
  for (int i = ty; i < 32; i += 8)
    dst[(size_t)(c0 + i) * 512 + (r0 + tx)] = f2bu(tile[tx][i]);
}

// ---------------- fused QKV projection v3 (round-15, unchanged) ----------------
__global__ __launch_bounds__(512, 1)
void gemm_qkv(const unsigned short* __restrict__ A,
              const unsigned short* __restrict__ B,
              unsigned short* __restrict__ Qo,
              unsigned short* __restrict__ Ko,
              unsigned short* __restrict__ Vo) {
  __shared__ __align__(16) char smem[131072];  // Abuf[2]:0,32K  Bbuf[2]:64K,96K
  const int tid = threadIdx.x, lane = tid & 63, w = tid >> 6;
  const int wm = w >> 2, wn = w & 3;
  const int bid = blockIdx.x;
  const int x = bid & 7, inner = bid >> 3;     // grid = 192*NB (%8==0)
  const int p0 = (x * 6 + inner % 6) * 256;    // n-tile strip per XCD
  const int p1 = (inner / 6) * 256;            // m-tile

  f32x4 acc[8][4];
  #pragma unroll
  for (int i = 0; i < 8; ++i)
    #pragma unroll
    for (int j = 0; j < 4; ++j)
      acc[i][j] = f32x4{0.f, 0.f, 0.f, 0.f};

  auto stage = [&](int t, int c) {           // 8 gload_lds / thread
    const int kt = t * 128;
    #pragma unroll
    for (int is = 0; is < 4; ++is) {
      const int ob = is * 8192 + w * 1024;
      const int ol = ob + lane * 16;
      const int row = ol >> 7, bo = ol & 127;
      const int sw = (row & 7) << 4;
      GLOAD_LDS16((const char*)A + (size_t)(p0 + row) * 1024 + kt + (bo ^ sw),
                  smem + c * 32768 + ob);
      GLOAD_LDS16((const char*)B + (size_t)(p1 + row) * 1024 + kt + (bo ^ sw),
                  smem + 65536 + c * 32768 + ob);
    }
  };

  stage(0, 0);
  stage(1, 1);
  asm volatile("s_waitcnt vmcnt(8)" ::: "memory");
  __builtin_amdgcn_sched_barrier(0);
  __builtin_amdgcn_s_barrier();

  for (int t = 0; t < 8; ++t) {
    const int c = t & 1;
    const char* Ab = smem + c * 32768;
    const char* Bb = smem + 65536 + c * 32768;
    #pragma unroll
    for (int ks = 0; ks < 2; ++ks) {
      bf16x8 af[8], bf[4];
      #pragma unroll
      for (int mi = 0; mi < 8; ++mi) {
        const int row = wm * 128 + mi * 16 + (lane & 15);
        af[mi] = *reinterpret_cast<const bf16x8*>(
            Ab + row * 128 + ((ks * 64 + ((lane >> 4) << 4)) ^ ((row & 7) << 4)));
      }
      #pragma unroll
      for (int ni = 0; ni < 4; ++ni) {
        const int row = wn * 64 + ni * 16 + (lane & 15);
        bf[ni] = *reinterpret_cast<const bf16x8*>(
            Bb + row * 128 + ((ks * 64 + ((lane >> 4) << 4)) ^ ((row & 7) << 4)));
      }
      #pragma unroll
      for (int mi = 0; mi < 8; ++mi)
        #pragma unroll
        for (int ni = 0; ni < 4; ++ni)
          acc[mi][ni] = __builtin_amdgcn_mfma_f32_16x16x32_bf16(af[mi], bf[ni], acc[mi][ni], 0, 0, 0);
    }
    asm volatile("" ::: "memory");
    __builtin_amdgcn_sched_barrier(0);
    __builtin_amdgcn_s_barrier();
    if (t + 2 < 8) stage(t + 2, c);
    if (t + 1 < 8) {
      if (t + 2 < 8) asm volatile("s_waitcnt vmcnt(8)" ::: "memory");
      else           asm volatile("s_waitcnt vmcnt(0)" ::: "memory");
      __builtin_amdgcn_sched_barrier(0);
      __builtin_amdgcn_s_barrier();
    }
  }

  const int region = p0 >> 12;
  if (region < 2) {
    const float qs = (region == 0) ? QK_SCALE_LOG2E : QK_SCALE;
    unsigned short* dst = (region == 0) ? Qo : Ko;
    #pragma unroll
    for (int mi = 0; mi < 8; ++mi) {
      #pragma unroll
      for (int ni = 0; ni < 4; ++ni) {
        const int n = p0 + wm * 128 + mi * 16 + ((lane >> 4) << 2);
        const int m = p1 + wn * 64 + ni * 16 + (lane & 15);
        const int b = m >> 10, t = m & 1023;
        const int nr = n & 4095, h = nr >> 9, d = nr & 511;
        ushort4 u;
        u.x = f2bu(acc[mi][ni][0] * qs); u.y = f2bu(acc[mi][ni][1] * qs);
        u.z = f2bu(acc[mi][ni][2] * qs); u.w = f2bu(acc[mi][ni][3] * qs);
        *reinterpret_cast<ushort4*>(&dst[((size_t)((b * NH + h) * T_SEQ + t)) * DH + d]) = u;
      }
    }
  } else {
    __builtin_amdgcn_sched_barrier(0);
    __builtin_amdgcn_s_barrier();
    unsigned short* Vl = reinterpret_cast<unsigned short*>(smem);  // [256][256] bf16
    #pragma unroll
    for (int mi = 0; mi < 8; ++mi) {
      #pragma unroll
      for (int ni = 0; ni < 4; ++ni) {
        const int dl0 = wm * 128 + mi * 16 + ((lane >> 4) << 2);
        const int tl = wn * 64 + ni * 16 + (lane & 15);
        #pragma unroll
        for (int r = 0; r < 4; ++r) {
          const int dl = dl0 + r;
          Vl[dl * 256 + (tl ^ ((dl & 7) << 3))] = f2bu(acc[mi][ni][r]);
        }
      }
    }
    __syncthreads();
    const int bb = p1 >> 10, t0 = p1 & 1023;
    const int hh = (p0 - 8192) >> 9, d0 = (p0 - 8192) & 511;
    unsigned short* vdst = Vo + ((size_t)(bb * NH + hh) * DH + d0) * T_SEQ + t0;
    #pragma unroll
    for (int i = 0; i < 16; ++i) {
      const int idx = i * 512 + tid;
      const int dr = idx >> 5, tc = (idx & 31) * 8;
      *reinterpret_cast<uint4*>(vdst + (size_t)dr * T_SEQ + tc) =
          *reinterpret_cast<const uint4*>(Vl + dr * 256 + (tc ^ ((dr & 7) << 3)));
    }
  }
}

// ---------------- output GEMM v2 (round-10, unchanged) ----------------
__global__ __launch_bounds__(256, 4)
void gemm_out(const unsigned short* __restrict__ A,   // Wut [512][4096]
              const unsigned short* __restrict__ B,   // Ob  [NB*1024][4096]
              const float* __restrict__ bias,
              float* __restrict__ C) {
  __shared__ __align__(16) char As[8192];
  __shared__ __align__(16) char Bs[16384];
  const int tid = threadIdx.x, lane = tid & 63, w = tid >> 6;
  const int bid = blockIdx.x;
  const int x = bid & 7, inner = bid >> 3;
  const int mtiles_per_xcd = gridDim.x >> 7;
  const int c0 = (inner & 15) * 32;
  const int m0 = (x * mtiles_per_xcd + (inner >> 4)) * 64;
  const int Kd = HK;

  f32x4 acc[2];
  acc[0] = f32x4{0.f, 0.f, 0.f, 0.f};
  acc[1] = f32x4{0.f, 0.f, 0.f, 0.f};

  for (int kt = 0; kt < Kd; kt += 128) {
    __syncthreads();
    #pragma unroll
    for (int is = 0; is < 2; ++is) {
      const int ob = is * 4096 + w * 1024;
      const int ol = ob + lane * 16;
      const int row = ol >> 8, bo = ol & 255;
      GLOAD_LDS16((const char*)A + ((size_t)(c0 + row) * Kd + kt) * 2 + (bo ^ ((row & 15) << 4)), As + ob);
    }
    #pragma unroll
    for (int is = 0; is < 4; ++is) {
      const int ob = is * 4096 + w * 1024;
      const int ol = ob + lane * 16;
      const int row = ol >> 8, bo = ol & 255;
      GLOAD_LDS16((const char*)B + ((size_t)(m0 + row) * Kd + kt) * 2 + (bo ^ ((row & 15) << 4)), Bs + ob);
    }
    __syncthreads();
    #pragma unroll
    for (int ks = 0; ks < 4; ++ks) {
      const int ko = ks * 64 + ((lane >> 4) << 4);
      bf16x8 af0, af1, bf;
      { const int row = (lane & 15);
        af0 = *reinterpret_cast<const bf16x8*>(As + row * 256 + (ko ^ ((row & 15) << 4))); }
      { const int row = 16 + (lane & 15);
        af1 = *reinterpret_cast<const bf16x8*>(As + row * 256 + (ko ^ ((row & 15) << 4))); }
      { const int row = w * 16 + (lane & 15);
        bf = *reinterpret_cast<const bf16x8*>(Bs + row * 256 + (ko ^ ((row & 15) << 4))); }
      acc[0] = __builtin_amdgcn_mfma_f32_16x16x32_bf16(af0, bf, acc[0], 0, 0, 0);
      acc[1] = __builtin_amdgcn_mfma_f32_16x16x32_bf16(af1, bf, acc[1], 0, 0, 0);
    }
  }

  const int m = m0 + w * 16 + (lane & 15);
  #pragma unroll
  for (int fc = 0; fc < 2; ++fc) {
    const int c = c0 + fc * 16 + ((lane >> 4) << 2);
    const float4 bn = *reinterpret_cast<const float4*>(&bias[c]);
    float4 v;
    v.x = acc[fc][0] + bn.x; v.y = acc[fc][1] + bn.y;
    v.z = acc[fc][2] + bn.z; v.w = acc[fc][3] + bn.w;
    *reinterpret_cast<float4*>(&C[(size_t)m * DH + c]) = v;
  }
}

// ---------------- flash attention v9: KVBLK=64, single-buffered, 4 barriers/step ----
// LDS: Ks 64x512 (64KB, swz (row&7)<<4) + Vts 512x64 (64KB rows 128B, granule-swz
// (row&7)<<4 with pre-swizzled global source) + S 64x64 f32 (16KB, 32B-granule swz)
// + P 64x64 bf16 (8KB, swz (r&7)<<4)  ~= 153KB, 1 block/CU.
// Per wave: QK 2 S-frags (rg=w>>1, cf={w&1, 2+(w&1)}) = 32 MFMA; PV 2x8 frags
// x K64 = 32 MFMA (rows 32*(w>>2)+, cols 128*(w&3)+).
__global__ __launch_bounds__(512, 1)
void attn_kernel(const unsigned short* __restrict__ Qg,
                 const unsigned short* __restrict__ Kg,
                 const unsigned short* __restrict__ Vtg,
                 unsigned short* __restrict__ Og) {
  __shared__ __align__(16) char Ks[65536];
  __shared__ __align__(16) char Vts[65536];
  __shared__ float S_lds[64 * 64];
  __shared__ __align__(16) char P_lds[64 * 128];
  __shared__ float Mrow[64], Lrow[64], Arow[64];
  __shared__ int rflag;

  const int tid = threadIdx.x, lane = tid & 63, w = tid >> 6;
  const int n = blockIdx.x;
  const int h = n & 7, p = (n >> 3) & 7, b = n >> 6;
  const int bh = b * NH + h;

  const unsigned short* Qbase = Qg + (size_t)bh * T_SEQ * DH;
  const char* Kbase = (const char*)(Kg + (size_t)bh * T_SEQ * DH);   // t-row stride 1024 B
  const char* Vbase = (const char*)(Vtg + (size_t)bh * DH * T_SEQ);  // d-row stride 2048 B

  // 16 gload/thread: K 64KB (linear dest; pre-swz src) + V 64KB (128B rows, granule swz)
  auto stage = [&](int st) {
    #pragma unroll
    for (int is = 0; is < 8; ++is) {
      const int ob = is * 8192 + tid * 16;
      { const int row = ob >> 10, bo = ob & 1023;
        GLOAD_LDS16(Kbase + (size_t)(st * 64 + row) * 1024 + (bo ^ ((row & 7) << 4)), Ks + ob); }
      { const int dr = ob >> 7, bo = ob & 127;
        GLOAD_LDS16(Vbase + (size_t)dr * 2048 + st * 128 + (bo ^ ((dr & 7) << 4)), Vts + ob); }
    }
  };

  for (int rep = 0; rep < 2; ++rep) {
    const int qt = rep ? 15 - p : p;
    const int nst = qt + 1;
    __syncthreads();  // guard stats/LDS from previous rep

    bf16x8 qreg[16];
    {
      const int qrow = qt * 64 + ((w >> 1) << 4) + (lane & 15);
      const unsigned short* qp = Qbase + (size_t)qrow * DH + ((lane >> 4) << 3);
      #pragma unroll
      for (int k2 = 0; k2 < 16; ++k2)
        qreg[k2] = *reinterpret_cast<const bf16x8*>(qp + k2 * 32);
    }

    f32x4 o[2][8];
    #pragma unroll
    for (int mi = 0; mi < 2; ++mi)
      #pragma unroll
      for (int ni = 0; ni < 8; ++ni)
        o[mi][ni] = f32x4{0.f, 0.f, 0.f, 0.f};

    if (tid < 64) { Mrow[tid] = -INFINITY; Lrow[tid] = 0.f; }

    for (int st = 0; st < nst; ++st) {
      __syncthreads();  // all waves done reading K/V of st-1 (and stats inited)
      stage(st);
      if (tid == 0) rflag = 0;
      __syncthreads();  // implicit vmcnt(0)+lgkmcnt(0): staged data visible

      // ---- QK: 2 S fragments per wave ----
      {
        const int rg = w >> 1;
        #pragma unroll
        for (int f = 0; f < 2; ++f) {
          const int cf = (w & 1) + f * 2;
          const int krow = cf * 16 + (lane & 15);
          const char* kr = Ks + krow * 1024;
          const int sw = (krow & 7) << 4;
          f32x4 s = f32x4{0.f, 0.f, 0.f, 0.f};
          __builtin_amdgcn_s_setprio(1);
          #pragma unroll
          for (int ks = 0; ks < 16; ++ks) {
            bf16x8 kf = *reinterpret_cast<const bf16x8*>(kr + ((ks * 64 + ((lane >> 4) << 4)) ^ sw));
            s = __builtin_amdgcn_mfma_f32_16x16x32_bf16(qreg[ks], kf, s, 0, 0, 0);
          }
          __builtin_amdgcn_s_setprio(0);
          const int col = cf * 16 + (lane & 15);
          const int rbase = rg * 16 + ((lane >> 4) << 2);
          #pragma unroll
          for (int r = 0; r < 4; ++r) {
            const int row = rbase + r;
            S_lds[row * 64 + (col ^ ((row & 7) << 3))] = s[r];
          }
        }
      }
      asm volatile("s_waitcnt lgkmcnt(0)" ::: "memory");
      __builtin_amdgcn_sched_barrier(0);
      __builtin_amdgcn_s_barrier();

      // ---- online softmax (log2 domain): 8 threads/row, 8 cols each ----
      {
        const int r = tid >> 3, cg = tid & 7;
        const int grow = qt * 64 + r;
        const int base = r * 64 + ((cg * 8) ^ ((r & 7) << 3));
        float sv[8];
        #pragma unroll
        for (int j = 0; j < 8; ++j) {
          const int c = cg * 8 + j;
          const float xv = S_lds[base + j];
          sv[j] = (st * 64 + c > grow) ? -INFINITY : xv;
        }
        float pm = sv[0];
        #pragma unroll
        for (int j = 1; j < 8; ++j) pm = fmaxf(pm, sv[j]);
        pm = fmaxf(pm, __shfl_xor(pm, 1));
        pm = fmaxf(pm, __shfl_xor(pm, 2));
        pm = fmaxf(pm, __shfl_xor(pm, 4));
        const float m_old = Mrow[r];
        const bool defer = (pm <= m_old + 11.0f);   // T13
        const float m_new = defer ? m_old : pm;
        float ps = 0.f;
        union { unsigned short s[8]; uint4 v; } pu;
        #pragma unroll
        for (int j = 0; j < 8; ++j) {
          const float pj = exp2f(sv[j] - m_new);
          ps += pj;
          pu.s[j] = f2bu(pj);
        }
        *reinterpret_cast<uint4*>(P_lds + r * 128 + ((cg * 16) ^ ((r & 7) << 4))) = pu.v;
        ps += __shfl_xor(ps, 1);
        ps += __shfl_xor(ps, 2);
        ps += __shfl_xor(ps, 4);
        if (cg == 0) {
          const float alpha = defer ? 1.0f : exp2f(m_old - m_new);
          if (!defer) { rflag = 1; Mrow[r] = m_new; }
          Arow[r] = alpha;
          Lrow[r] = alpha * Lrow[r] + ps;
        }
      }
      asm volatile("s_waitcnt lgkmcnt(0)" ::: "memory");
      __builtin_amdgcn_sched_barrier(0);
      __builtin_amdgcn_s_barrier();

      // ---- PV: K=64 contraction (2 kt-halves), rows 32*(w>>2)+, cols 128*(w&3)+ ----
      {
        bf16x8 pf[2][2];  // [mi][kt_half]
        #pragma unroll
        for (int mi = 0; mi < 2; ++mi) {
          const int pr = ((w >> 2) << 5) + mi * 16 + (lane & 15);
          const char* prow = P_lds + pr * 128;
          const int sw = (pr & 7) << 4;
          #pragma unroll
          for (int hh2 = 0; hh2 < 2; ++hh2)
            pf[mi][hh2] = *reinterpret_cast<const bf16x8*>(
                prow + ((hh2 * 64 + ((lane >> 4) << 4)) ^ sw));
        }
        if (rflag) {
          #pragma unroll
          for (int mi = 0; mi < 2; ++mi) {
            const int rb = ((w >> 2) << 5) + mi * 16 + ((lane >> 4) << 2);
            const f32x4 al = f32x4{Arow[rb], Arow[rb + 1], Arow[rb + 2], Arow[rb + 3]};
            #pragma unroll
            for (int ni = 0; ni < 8; ++ni) o[mi][ni] *= al;
          }
        }
        __builtin_amdgcn_s_setprio(1);
        #pragma unroll
        for (int ni = 0; ni < 8; ++ni) {
          const int vr = ((w & 3) << 7) + ni * 16 + (lane & 15);
          const char* vrow = Vts + vr * 128;
          const int sw = (vr & 7) << 4;
          #pragma unroll
          for (int hh2 = 0; hh2 < 2; ++hh2) {
            bf16x8 vf = *reinterpret_cast<const bf16x8*>(
                vrow + ((hh2 * 64 + ((lane >> 4) << 4)) ^ sw));
            o[0][ni] = __builtin_amdgcn_mfma_f32_16x16x32_bf16(pf[0][hh2], vf, o[0][ni], 0, 0, 0);
            o[1][ni] = __builtin_amdgcn_mfma_f32_16x16x32_bf16(pf[1][hh2], vf, o[1][ni], 0, 0, 0);
          }
        }
        __builtin_amdgcn_s_setprio(0);
      }
    }

    // normalize and store (O layout (b,t,h,d))
    #pragma unroll
    for (int mi = 0; mi < 2; ++mi) {
      const int rb = ((w >> 2) << 5) + mi * 16 + ((lane >> 4) << 2);
      f32x4 li;
      #pragma unroll
      for (int r = 0; r < 4; ++r) li[r] = 1.f / Lrow[rb + r];
      #pragma unroll
      for (int ni = 0; ni < 8; ++ni) {
        const int d = ((w & 3) << 7) + ni * 16 + (lane & 15);
        const size_t base = ((size_t)(b * T_SEQ + qt * 64 + rb) * NH + h) * DH + d;
        #pragma unroll
        for (int r = 0; r < 4; ++r)
          Og[base + (size_t)r * NH * DH] = f2bu(o[mi][ni][r] * li[r]);
      }
    }
  }
}

// ---------------- host launch (adaptive workspace chunking) ----------------
extern "C" void kernel_launch(void* const* d_in, const int* in_sizes, int n_in,
                              void* d_out, int out_size, void* d_ws, size_t ws_size,
                              hipStream_t stream) {
  (void)in_sizes; (void)n_in; (void)out_size;
  const float* x  = (const float*)d_in[0];
  const float* Wq = (const float*)d_in[1];
  const float* Wk = (const float*)d_in[2];
  const float* Wv = (const float*)d_in[3];
  const float* Wu = (const float*)d_in[4];
  const float* bu = (const float*)d_in[5];
  float* out = (float*)d_out;

  const size_t PERS = (size_t)8192 * 512 * 2 + 3 * (size_t)4096 * 512 * 2 + (size_t)512 * 4096 * 2;
  int NB = 8;
  while (NB > 1 && PERS + 4 * ((size_t)NB * 1024 * 4096 * 2) + 65536 > ws_size) NB >>= 1;

  size_t off = 0;
  auto wsp = [&](size_t bytes) {
    char* p = (char*)d_ws + off;
    off += (bytes + 255) & ~(size_t)255;
    return p;
  };
  unsigned short* xb   = (unsigned short*)wsp((size_t)8192 * 512 * 2);
  unsigned short* Wcat = (unsigned short*)wsp(3 * (size_t)4096 * 512 * 2);  // Wq^T|Wk^T|Wv^T
  unsigned short* Wut  = (unsigned short*)wsp((size_t)512 * 4096 * 2);
  const size_t CHB = (size_t)NB * 1024 * 4096 * 2;
  unsigned short* Qc = (unsigned short*)wsp(CHB);
  unsigned short* Kc = (unsigned short*)wsp(CHB);
  unsigned short* Vc = (unsigned short*)wsp(CHB);
  unsigned short* Oc = (unsigned short*)wsp(CHB);

  cvt_bf16_kernel<<<4096, 256, 0, stream>>>(x, xb, 8192 * 512 / 4);
  transpose_cvt3_kernel<<<dim3(128, 16, 3), dim3(32, 8), 0, stream>>>(Wq, Wk, Wv, Wcat);
  transpose_cvt_kernel<<<dim3(16, 128), dim3(32, 8), 0, stream>>>(Wu, Wut, 4096, 512);

  const int nchunks = 8 / NB;
  for (int c = 0; c < nchunks; ++c) {
    const unsigned short* xc = xb + (size_t)c * NB * 1024 * 512;
    gemm_qkv<<<192 * NB, 512, 0, stream>>>(Wcat, xc, Qc, Kc, Vc);
    attn_kernel<<<64 * NB, 512, 0, stream>>>(Qc, Kc, Vc, Oc);
    gemm_out<<<256 * NB, 256, 0, stream>>>(Wut, Oc, bu, out + (size_t)c * NB * 1024 * 512);
  }
}

// Round 17
// 398.023 us; speedup vs baseline: 1.2061x; 1.2061x over previous
//
#include <hip/hip_runtime.h>
#include <hip/hip_bf16.h>

#define T_SEQ 1024
#define NH 8
#define DH 512
#define HK 4096

typedef __attribute__((ext_vector_type(8))) __bf16 bf16x8;
typedef __attribute__((ext_vector_type(4))) float f32x4;

#define QK_SCALE 0.21022410381342863f           // 512^-0.25
#define QK_SCALE_LOG2E 0.30328926584f           // QK_SCALE * log2(e): Q side -> exp2 domain

static __device__ __forceinline__ unsigned short f2bu(float f) {
  union { __hip_bfloat16 h; unsigned short u; } cv;
  cv.h = __float2bfloat16(f);
  return cv.u;
}

#define GLOAD_LDS16(gsrc, ldst) \
  __builtin_amdgcn_global_load_lds((const __attribute__((address_space(1))) void*)(gsrc), \
                                   (__attribute__((address_space(3))) void*)(ldst), 16, 0, 0)

// ---------------- convert / transpose ----------------
__global__ void cvt_bf16_kernel(const float* __restrict__ in, unsigned short* __restrict__ out, int n4) {
  int i = blockIdx.x * blockDim.x + threadIdx.x;
  if (i >= n4) return;
  const float4 v = reinterpret_cast<const float4*>(in)[i];
  ushort4 u; u.x = f2bu(v.x); u.y = f2bu(v.y); u.z = f2bu(v.z); u.w = f2bu(v.w);
  reinterpret_cast<ushort4*>(out)[i] = u;
}

// out[C][R] = bf16(in[R][C])
__global__ void transpose_cvt_kernel(const float* __restrict__ in, unsigned short* __restrict__ out,
                                     int R, int C) {
  __shared__ float tile[32][33];
  const int c0 = blockIdx.x * 32, r0 = blockIdx.y * 32;
  const int tx = threadIdx.x, ty = threadIdx.y;
  #pragma unroll
  for (int i = ty; i < 32; i += 8)
    tile[i][tx] = in[(size_t)(r0 + i) * C + (c0 + tx)];
  __syncthreads();
  #pragma unroll
  for (int i = ty; i < 32; i += 8)
    out[(size_t)(c0 + i) * R + (r0 + tx)] = f2bu(tile[tx][i]);
}

// fused: transposes Wq/Wk/Wv (each [512][4096]) into Wcat [12288][512], z selects source.
__global__ void transpose_cvt3_kernel(const float* __restrict__ Wq, const float* __restrict__ Wk,
                                      const float* __restrict__ Wv, unsigned short* __restrict__ out) {
  __shared__ float tile[32][33];
  const float* in = (blockIdx.z == 0) ? Wq : (blockIdx.z == 1) ? Wk : Wv;
  unsigned short* dst = out + (size_t)blockIdx.z * 4096 * 512;
  const int c0 = blockIdx.x * 32, r0 = blockIdx.y * 32;
  const int tx = threadIdx.x, ty = threadIdx.y;
  #pragma unroll
  for (int i = ty; i < 32; i += 8)
    tile[i][tx] = in[(size_t)(r0 + i) * 4096 + (c0 + tx)];
  __syncthreads();
  #pragma unroll
  for (int i = ty; i < 32; i += 8)
    dst[(size_t)(c0 + i) * 512 + (r0 + tx)] = f2bu(tile[tx][i]);
}

// ---------------- fused QKV projection v3b: counted-vmcnt dbuf + coalesced Q/K epilogue --
__global__ __launch_bounds__(512, 1)
void gemm_qkv(const unsigned short* __restrict__ A,
              const unsigned short* __restrict__ B,
              unsigned short* __restrict__ Qo,
              unsigned short* __restrict__ Ko,
              unsigned short* __restrict__ Vo) {
  __shared__ __align__(16) char smem[131072];  // Abuf[2]:0,32K  Bbuf[2]:64K,96K
  const int tid = threadIdx.x, lane = tid & 63, w = tid >> 6;
  const int wm = w >> 2, wn = w & 3;
  const int bid = blockIdx.x;
  const int x = bid & 7, inner = bid >> 3;     // grid = 192*NB (%8==0)
  const int p0 = (x * 6 + inner % 6) * 256;    // n-tile strip per XCD
  const int p1 = (inner / 6) * 256;            // m-tile

  f32x4 acc[8][4];
  #pragma unroll
  for (int i = 0; i < 8; ++i)
    #pragma unroll
    for (int j = 0; j < 4; ++j)
      acc[i][j] = f32x4{0.f, 0.f, 0.f, 0.f};

  auto stage = [&](int t, int c) {           // 8 gload_lds / thread
    const int kt = t * 128;
    #pragma unroll
    for (int is = 0; is < 4; ++is) {
      const int ob = is * 8192 + w * 1024;
      const int ol = ob + lane * 16;
      const int row = ol >> 7, bo = ol & 127;
      const int sw = (row & 7) << 4;
      GLOAD_LDS16((const char*)A + (size_t)(p0 + row) * 1024 + kt + (bo ^ sw),
                  smem + c * 32768 + ob);
      GLOAD_LDS16((const char*)B + (size_t)(p1 + row) * 1024 + kt + (bo ^ sw),
                  smem + 65536 + c * 32768 + ob);
    }
  };

  stage(0, 0);
  stage(1, 1);
  asm volatile("s_waitcnt vmcnt(8)" ::: "memory");
  __builtin_amdgcn_sched_barrier(0);
  __builtin_amdgcn_s_barrier();

  for (int t = 0; t < 8; ++t) {
    const int c = t & 1;
    const char* Ab = smem + c * 32768;
    const char* Bb = smem + 65536 + c * 32768;
    #pragma unroll
    for (int ks = 0; ks < 2; ++ks) {
      bf16x8 af[8], bf[4];
      #pragma unroll
      for (int mi = 0; mi < 8; ++mi) {
        const int row = wm * 128 + mi * 16 + (lane & 15);
        af[mi] = *reinterpret_cast<const bf16x8*>(
            Ab + row * 128 + ((ks * 64 + ((lane >> 4) << 4)) ^ ((row & 7) << 4)));
      }
      #pragma unroll
      for (int ni = 0; ni < 4; ++ni) {
        const int row = wn * 64 + ni * 16 + (lane & 15);
        bf[ni] = *reinterpret_cast<const bf16x8*>(
            Bb + row * 128 + ((ks * 64 + ((lane >> 4) << 4)) ^ ((row & 7) << 4)));
      }
      #pragma unroll
      for (int mi = 0; mi < 8; ++mi)
        #pragma unroll
        for (int ni = 0; ni < 4; ++ni)
          acc[mi][ni] = __builtin_amdgcn_mfma_f32_16x16x32_bf16(af[mi], bf[ni], acc[mi][ni], 0, 0, 0);
    }
    asm volatile("" ::: "memory");
    __builtin_amdgcn_sched_barrier(0);
    __builtin_amdgcn_s_barrier();
    if (t + 2 < 8) stage(t + 2, c);
    if (t + 1 < 8) {
      if (t + 2 < 8) asm volatile("s_waitcnt vmcnt(8)" ::: "memory");
      else           asm volatile("s_waitcnt vmcnt(0)" ::: "memory");
      __builtin_amdgcn_sched_barrier(0);
      __builtin_amdgcn_s_barrier();
    }
  }
  // post-loop: all waves past the t=7 post-compute barrier; all loads drained -> smem free

  const int region = p0 >> 12;
  if (region < 2) {
    // Q/K: stage [t][d] in LDS (16B-granule XOR (tl&7)<<4; write 2-way max, read
    // conflict-free), then 16 coalesced uint4 stores/thread along d.
    const float qs = (region == 0) ? QK_SCALE_LOG2E : QK_SCALE;
    unsigned short* dst = (region == 0) ? Qo : Ko;
    unsigned short* Tl = reinterpret_cast<unsigned short*>(smem);  // [256 t][256 d] = 128KB
    #pragma unroll
    for (int mi = 0; mi < 8; ++mi) {
      #pragma unroll
      for (int ni = 0; ni < 4; ++ni) {
        const int dl0 = wm * 128 + mi * 16 + ((lane >> 4) << 2);   // 8B-aligned, within granule
        const int tl = wn * 64 + ni * 16 + (lane & 15);
        ushort4 u;
        u.x = f2bu(acc[mi][ni][0] * qs); u.y = f2bu(acc[mi][ni][1] * qs);
        u.z = f2bu(acc[mi][ni][2] * qs); u.w = f2bu(acc[mi][ni][3] * qs);
        *reinterpret_cast<ushort4*>((char*)Tl + (size_t)tl * 512 + ((dl0 * 2) ^ ((tl & 7) << 4))) = u;
      }
    }
    __syncthreads();
    const int bb = p1 >> 10, t0 = p1 & 1023;
    const int hh = (p0 & 4095) >> 9, d0 = p0 & 511;
    unsigned short* qdst = dst + ((size_t)(bb * NH + hh) * T_SEQ + t0) * DH + d0;
    #pragma unroll
    for (int i = 0; i < 16; ++i) {
      const int idx = i * 512 + tid;                 // 0..8191
      const int tr = idx >> 5, dc = (idx & 31) * 16; // byte offset in 512B row
      *reinterpret_cast<uint4*>((char*)qdst + (size_t)tr * DH * 2 + dc) =
          *reinterpret_cast<const uint4*>((char*)Tl + (size_t)tr * 512 + (dc ^ ((tr & 7) << 4)));
    }
  } else {
    unsigned short* Vl = reinterpret_cast<unsigned short*>(smem);  // [256 d][256 t] bf16
    #pragma unroll
    for (int mi = 0; mi < 8; ++mi) {
      #pragma unroll
      for (int ni = 0; ni < 4; ++ni) {
        const int dl0 = wm * 128 + mi * 16 + ((lane >> 4) << 2);
        const int tl = wn * 64 + ni * 16 + (lane & 15);
        #pragma unroll
        for (int r = 0; r < 4; ++r) {
          const int dl = dl0 + r;
          Vl[dl * 256 + (tl ^ ((dl & 7) << 3))] = f2bu(acc[mi][ni][r]);
        }
      }
    }
    __syncthreads();
    const int bb = p1 >> 10, t0 = p1 & 1023;
    const int hh = (p0 - 8192) >> 9, d0 = (p0 - 8192) & 511;
    unsigned short* vdst = Vo + ((size_t)(bb * NH + hh) * DH + d0) * T_SEQ + t0;
    #pragma unroll
    for (int i = 0; i < 16; ++i) {
      const int idx = i * 512 + tid;
      const int dr = idx >> 5, tc = (idx & 31) * 8;
      *reinterpret_cast<uint4*>(vdst + (size_t)dr * T_SEQ + tc) =
          *reinterpret_cast<const uint4*>(Vl + dr * 256 + (tc ^ ((dr & 7) << 3)));
    }
  }
}

// ---------------- output GEMM v2 (round-10, unchanged) ----------------
__global__ __launch_bounds__(256, 4)
void gemm_out(const unsigned short* __restrict__ A,   // Wut [512][4096]
              const unsigned short* __restrict__ B,   // Ob  [NB*1024][4096]
              const float* __restrict__ bias,
              float* __restrict__ C) {
  __shared__ __align__(16) char As[8192];
  __shared__ __align__(16) char Bs[16384];
  const int tid = threadIdx.x, lane = tid & 63, w = tid >> 6;
  const int bid = blockIdx.x;
  const int x = bid & 7, inner = bid >> 3;
  const int mtiles_per_xcd = gridDim.x >> 7;
  const int c0 = (inner & 15) * 32;
  const int m0 = (x * mtiles_per_xcd + (inner >> 4)) * 64;
  const int Kd = HK;

  f32x4 acc[2];
  acc[0] = f32x4{0.f, 0.f, 0.f, 0.f};
  acc[1] = f32x4{0.f, 0.f, 0.f, 0.f};

  for (int kt = 0; kt < Kd; kt += 128) {
    __syncthreads();
    #pragma unroll
    for (int is = 0; is < 2; ++is) {
      const int ob = is * 4096 + w * 1024;
      const int ol = ob + lane * 16;
      const int row = ol >> 8, bo = ol & 255;
      GLOAD_LDS16((const char*)A + ((size_t)(c0 + row) * Kd + kt) * 2 + (bo ^ ((row & 15) << 4)), As + ob);
    }
    #pragma unroll
    for (int is = 0; is < 4; ++is) {
      const int ob = is * 4096 + w * 1024;
      const int ol = ob + lane * 16;
      const int row = ol >> 8, bo = ol & 255;
      GLOAD_LDS16((const char*)B + ((size_t)(m0 + row) * Kd + kt) * 2 + (bo ^ ((row & 15) << 4)), Bs + ob);
    }
    __syncthreads();
    #pragma unroll
    for (int ks = 0; ks < 4; ++ks) {
      const int ko = ks * 64 + ((lane >> 4) << 4);
      bf16x8 af0, af1, bf;
      { const int row = (lane & 15);
        af0 = *reinterpret_cast<const bf16x8*>(As + row * 256 + (ko ^ ((row & 15) << 4))); }
      { const int row = 16 + (lane & 15);
        af1 = *reinterpret_cast<const bf16x8*>(As + row * 256 + (ko ^ ((row & 15) << 4))); }
      { const int row = w * 16 + (lane & 15);
        bf = *reinterpret_cast<const bf16x8*>(Bs + row * 256 + (ko ^ ((row & 15) << 4))); }
      acc[0] = __builtin_amdgcn_mfma_f32_16x16x32_bf16(af0, bf, acc[0], 0, 0, 0);
      acc[1] = __builtin_amdgcn_mfma_f32_16x16x32_bf16(af1, bf, acc[1], 0, 0, 0);
    }
  }

  const int m = m0 + w * 16 + (lane & 15);
  #pragma unroll
  for (int fc = 0; fc < 2; ++fc) {
    const int c = c0 + fc * 16 + ((lane >> 4) << 2);
    const float4 bn = *reinterpret_cast<const float4*>(&bias[c]);
    float4 v;
    v.x = acc[fc][0] + bn.x; v.y = acc[fc][1] + bn.y;
    v.z = acc[fc][2] + bn.z; v.w = acc[fc][3] + bn.w;
    *reinterpret_cast<float4*>(&C[(size_t)m * DH + c]) = v;
  }
}

// ---------------- flash attention v4c (round-15 proven version, reverted) ----------------
__global__ __launch_bounds__(512, 1)
void attn_kernel(const unsigned short* __restrict__ Qg,
                 const unsigned short* __restrict__ Kg,
                 const unsigned short* __restrict__ Vtg,
                 unsigned short* __restrict__ Og) {
  __shared__ __align__(16) char Ks[2][32768];      // 32 x 512 bf16, row-swz (row&7)<<4
  __shared__ __align__(16) char Vts[2][32768];     // 512 x 32 bf16, row-swz (row&3)<<4
  __shared__ float S_lds[64 * 32];                 // stride 32 + col^((row&7)<<2)
  __shared__ __align__(16) char P_lds[64 * 64];    // 64 x 32 bf16, swz (r&3)<<4
  __shared__ float Mrow[64], Lrow[64], Arow[64];
  __shared__ int rflag;

  const int tid = threadIdx.x, lane = tid & 63, w = tid >> 6;
  const int n = blockIdx.x;
  const int h = n & 7, p = (n >> 3) & 7, b = n >> 6;
  const int bh = b * NH + h;

  const unsigned short* Qbase = Qg + (size_t)bh * T_SEQ * DH;
  const char* Kbase = (const char*)(Kg + (size_t)bh * T_SEQ * DH);   // t-row stride 1024 B
  const char* Vbase = (const char*)(Vtg + (size_t)bh * DH * T_SEQ);  // d-row stride 2048 B

  auto stage = [&](int st, int buf) {
    #pragma unroll
    for (int is = 0; is < 4; ++is) {
      const int ob = is * 8192 + w * 1024;
      const int ol = ob + lane * 16;
      { const int row = ol >> 10, bo = ol & 1023;
        GLOAD_LDS16(Kbase + (size_t)(st * 32 + row) * 1024 + (bo ^ ((row & 7) << 4)), Ks[buf] + ob); }
      { const int row = ol >> 6, bo = ol & 63;
        GLOAD_LDS16(Vbase + (size_t)row * 2048 + st * 64 + (bo ^ ((row & 3) << 4)), Vts[buf] + ob); }
    }
  };

  for (int rep = 0; rep < 2; ++rep) {
    const int qt = rep ? 15 - p : p;
    const int nst = 2 * qt + 2;
    __syncthreads();  // guard stats/LDS from previous rep

    bf16x8 qreg[16];
    {
      const int qrow = qt * 64 + ((w >> 1) << 4) + (lane & 15);
      const unsigned short* qp = Qbase + (size_t)qrow * DH + ((lane >> 4) << 3);
      #pragma unroll
      for (int k2 = 0; k2 < 16; ++k2)
        qreg[k2] = *reinterpret_cast<const bf16x8*>(qp + k2 * 32);
    }

    f32x4 o[2][8];
    #pragma unroll
    for (int mi = 0; mi < 2; ++mi)
      #pragma unroll
      for (int ni = 0; ni < 8; ++ni)
        o[mi][ni] = f32x4{0.f, 0.f, 0.f, 0.f};

    if (tid < 64) { Mrow[tid] = -INFINITY; Lrow[tid] = 0.f; }

    int cur = 0;
    stage(0, 0);

    for (int st = 0; st < nst; ++st) {
      __syncthreads();  // implicit vmcnt(0): stage(st) complete + all LDS quiesced
      if (st + 1 < nst) stage(st + 1, cur ^ 1);  // in flight across raw barriers below
      if (tid == 0) rflag = 0;

      // ---- QK: wave w computes S fragment (w>>1, w&1); 2 independent partials ----
      {
        const int krow = ((w & 1) << 4) + (lane & 15);
        const char* kr = Ks[cur] + krow * 1024;
        const int sw = (krow & 7) << 4;
        f32x4 sA = f32x4{0.f, 0.f, 0.f, 0.f};
        f32x4 sB = f32x4{0.f, 0.f, 0.f, 0.f};
        __builtin_amdgcn_s_setprio(1);
        #pragma unroll
        for (int ks = 0; ks < 16; ks += 2) {
          bf16x8 kf0 = *reinterpret_cast<const bf16x8*>(kr + ((ks * 64 + ((lane >> 4) << 4)) ^ sw));
          bf16x8 kf1 = *reinterpret_cast<const bf16x8*>(kr + (((ks + 1) * 64 + ((lane >> 4) << 4)) ^ sw));
          sA = __builtin_amdgcn_mfma_f32_16x16x32_bf16(qreg[ks], kf0, sA, 0, 0, 0);
          sB = __builtin_amdgcn_mfma_f32_16x16x32_bf16(qreg[ks + 1], kf1, sB, 0, 0, 0);
        }
        __builtin_amdgcn_s_setprio(0);
        const f32x4 s = sA + sB;
        const int col = ((w & 1) << 4) + (lane & 15);
        const int rbase = ((w >> 1) << 4) + ((lane >> 4) << 2);
        #pragma unroll
        for (int r = 0; r < 4; ++r)
          S_lds[(rbase + r) * 32 + (col ^ (((rbase + r) & 7) << 2))] = s[r];
      }
      asm volatile("s_waitcnt lgkmcnt(0)" ::: "memory");
      __builtin_amdgcn_sched_barrier(0);
      __builtin_amdgcn_s_barrier();   // raw: staged loads stay in flight

      // ---- online softmax (log2 domain): 8 threads per row, 64 rows ----
      {
        const int r = tid >> 3, cg = tid & 7;
        const int grow = qt * 64 + r;
        const int base = r * 32 + ((cg * 4) ^ ((r & 7) << 2));
        float sv[4];
        #pragma unroll
        for (int j = 0; j < 4; ++j) {
          const int c = cg * 4 + j;
          const float x = S_lds[base + j];
          sv[j] = (st * 32 + c > grow) ? -INFINITY : x;
        }
        float pm = fmaxf(fmaxf(sv[0], sv[1]), fmaxf(sv[2], sv[3]));
        pm = fmaxf(pm, __shfl_xor(pm, 1));
        pm = fmaxf(pm, __shfl_xor(pm, 2));
        pm = fmaxf(pm, __shfl_xor(pm, 4));
        const float m_old = Mrow[r];
        const bool defer = (pm <= m_old + 11.0f);   // T13
        const float m_new = defer ? m_old : pm;
        float ps;
        ushort4 pu;
        { float p0 = exp2f(sv[0] - m_new), p1 = exp2f(sv[1] - m_new),
                p2 = exp2f(sv[2] - m_new), p3 = exp2f(sv[3] - m_new);
          ps = p0 + p1 + p2 + p3;
          pu.x = f2bu(p0); pu.y = f2bu(p1); pu.z = f2bu(p2); pu.w = f2bu(p3); }
        *reinterpret_cast<ushort4*>(P_lds + r * 64 + ((cg * 8) ^ ((r & 3) << 4))) = pu;
        ps += __shfl_xor(ps, 1);
        ps += __shfl_xor(ps, 2);
        ps += __shfl_xor(ps, 4);
        if (cg == 0) {
          const float alpha = defer ? 1.0f : exp2f(m_old - m_new);
          if (!defer) { rflag = 1; Mrow[r] = m_new; }
          Arow[r] = alpha;
          Lrow[r] = alpha * Lrow[r] + ps;
        }
      }
      asm volatile("s_waitcnt lgkmcnt(0)" ::: "memory");
      __builtin_amdgcn_sched_barrier(0);
      __builtin_amdgcn_s_barrier();   // raw

      // ---- PV: wave w -> O rows 32*(w>>2)+, cols 128*(w&3)+ ----
      {
        bf16x8 pf[2];
        #pragma unroll
        for (int mi = 0; mi < 2; ++mi) {
          const int pr = ((w >> 2) << 5) + mi * 16 + (lane & 15);
          pf[mi] = *reinterpret_cast<const bf16x8*>(
              P_lds + pr * 64 + ((((lane >> 4) << 4)) ^ ((pr & 3) << 4)));
        }
        if (rflag) {  // skip O-rescale when no row rescaled this step
          #pragma unroll
          for (int mi = 0; mi < 2; ++mi) {
            const int rb = ((w >> 2) << 5) + mi * 16 + ((lane >> 4) << 2);
            const f32x4 al = f32x4{Arow[rb], Arow[rb + 1], Arow[rb + 2], Arow[rb + 3]};
            #pragma unroll
            for (int ni = 0; ni < 8; ++ni) o[mi][ni] *= al;
          }
        }
        __builtin_amdgcn_s_setprio(1);
        #pragma unroll
        for (int ni = 0; ni < 8; ++ni) {
          const int vr = ((w & 3) << 7) + ni * 16 + (lane & 15);
          bf16x8 vf = *reinterpret_cast<const bf16x8*>(
              Vts[cur] + vr * 64 + ((((lane >> 4) << 4)) ^ ((vr & 3) << 4)));
          o[0][ni] = __builtin_amdgcn_mfma_f32_16x16x32_bf16(pf[0], vf, o[0][ni], 0, 0, 0);
          o[1][ni] = __builtin_amdgcn_mfma_f32_16x16x32_bf16(pf[1], vf, o[1][ni], 0, 0, 0);
        }
        __builtin_amdgcn_s_setprio(0);
      }
      cur ^= 1;
    }

    // normalize and store (O layout (b,t,h,d))
    #pragma unroll
    for (int mi = 0; mi < 2; ++mi) {
      const int rb = ((w >> 2) << 5) + mi * 16 + ((lane >> 4) << 2);
      f32x4 li;
      #pragma unroll
      for (int r = 0; r < 4; ++r) li[r] = 1.f / Lrow[rb + r];
      #pragma unroll
      for (int ni = 0; ni < 8; ++ni) {
        const int d = ((w & 3) << 7) + ni * 16 + (lane & 15);
        const size_t base = ((size_t)(b * T_SEQ + qt * 64 + rb) * NH + h) * DH + d;
        #pragma unroll
        for (int r = 0; r < 4; ++r)
          Og[base + (size_t)r * NH * DH] = f2bu(o[mi][ni][r] * li[r]);
      }
    }
  }
}

// ---------------- host launch (adaptive workspace chunking) ----------------
extern "C" void kernel_launch(void* const* d_in, const int* in_sizes, int n_in,
                              void* d_out, int out_size, void* d_ws, size_t ws_size,
                              hipStream_t stream) {
  (void)in_sizes; (void)n_in; (void)out_size;
  const float* x  = (const float*)d_in[0];
  const float* Wq = (const float*)d_in[1];
  const float* Wk = (const float*)d_in[2];
  const float* Wv = (const float*)d_in[3];
  const float* Wu = (const float*)d_in[4];
  const float* bu = (const float*)d_in[5];
  float* out = (float*)d_out;

  const size_t PERS = (size_t)8192 * 512 * 2 + 3 * (size_t)4096 * 512 * 2 + (size_t)512 * 4096 * 2;
  int NB = 8;
  while (NB > 1 && PERS + 4 * ((size_t)NB * 1024 * 4096 * 2) + 65536 > ws_size) NB >>= 1;

  size_t off = 0;
  auto wsp = [&](size_t bytes) {
    char* p = (char*)d_ws + off;
    off += (bytes + 255) & ~(size_t)255;
    return p;
  };
  unsigned short* xb   = (unsigned short*)wsp((size_t)8192 * 512 * 2);
  unsigned short* Wcat = (unsigned short*)wsp(3 * (size_t)4096 * 512 * 2);  // Wq^T|Wk^T|Wv^T
  unsigned short* Wut  = (unsigned short*)wsp((size_t)512 * 4096 * 2);
  const size_t CHB = (size_t)NB * 1024 * 4096 * 2;
  unsigned short* Qc = (unsigned short*)wsp(CHB);
  unsigned short* Kc = (unsigned short*)wsp(CHB);
  unsigned short* Vc = (unsigned short*)wsp(CHB);
  unsigned short* Oc = (unsigned short*)wsp(CHB);

  cvt_bf16_kernel<<<4096, 256, 0, stream>>>(x, xb, 8192 * 512 / 4);
  transpose_cvt3_kernel<<<dim3(128, 16, 3), dim3(32, 8), 0, stream>>>(Wq, Wk, Wv, Wcat);
  transpose_cvt_kernel<<<dim3(16, 128), dim3(32, 8), 0, stream>>>(Wu, Wut, 4096, 512);

  const int nchunks = 8 / NB;
  for (int c = 0; c < nchunks; ++c) {
    const unsigned short* xc = xb + (size_t)c * NB * 1024 * 512;
    gemm_qkv<<<192 * NB, 512, 0, stream>>>(Wcat, xc, Qc, Kc, Vc);
    attn_kernel<<<64 * NB, 512, 0, stream>>>(Qc, Kc, Vc, Oc);
    gemm_out<<<256 * NB, 256, 0, stream>>>(Wut, Oc, bu, out + (size_t)c * NB * 1024 * 512);
  }
}

// Round 18
// 392.648 us; speedup vs baseline: 1.2226x; 1.0137x over previous
//
#include <hip/hip_runtime.h>
#include <hip/hip_bf16.h>

#define T_SEQ 1024
#define NH 8
#define DH 512
#define HK 4096

typedef __attribute__((ext_vector_type(8))) __bf16 bf16x8;
typedef __attribute__((ext_vector_type(4))) float f32x4;

#define QK_SCALE 0.21022410381342863f           // 512^-0.25
#define QK_SCALE_LOG2E 0.30328926584f           // QK_SCALE * log2(e): Q side -> exp2 domain

static __device__ __forceinline__ unsigned short f2bu(float f) {
  union { __hip_bfloat16 h; unsigned short u; } cv;
  cv.h = __float2bfloat16(f);
  return cv.u;
}

#define GLOAD_LDS16(gsrc, ldst) \
  __builtin_amdgcn_global_load_lds((const __attribute__((address_space(1))) void*)(gsrc), \
                                   (__attribute__((address_space(3))) void*)(ldst), 16, 0, 0)

// ---------------- fused preamble: x->bf16 + W transposes, ONE launch ----------------
// bid < 2048            : cvt x (2048 blk x 256 thr x 2 float4 = 1,048,576 float4)
// 2048 <= bid < 8192+2048: transpose tiles. ti<6144 -> Wq/Wk/Wv (z=ti/2048,
//                          within: c-tile=within%128 over 4096, r-tile=within/128 over 512)
//                          ti>=6144 -> Wu (c-tile=t2%16 over 512, r-tile=t2/16 over 4096)
__global__ __launch_bounds__(256)
void preamble_kernel(const float* __restrict__ x,
                     const float* __restrict__ Wq, const float* __restrict__ Wk,
                     const float* __restrict__ Wv, const float* __restrict__ Wu,
                     unsigned short* __restrict__ xb,
                     unsigned short* __restrict__ Wcat,
                     unsigned short* __restrict__ Wut) {
  const int bid = blockIdx.x;
  if (bid < 2048) {
    int i = bid * 512 + threadIdx.x;
    #pragma unroll
    for (int r = 0; r < 2; ++r, i += 256) {
      const float4 v = reinterpret_cast<const float4*>(x)[i];
      ushort4 u; u.x = f2bu(v.x); u.y = f2bu(v.y); u.z = f2bu(v.z); u.w = f2bu(v.w);
      reinterpret_cast<ushort4*>(xb)[i] = u;
    }
    return;
  }
  __shared__ float tile[32][33];
  const int tx = threadIdx.x & 31, ty = threadIdx.x >> 5;   // 32 x 8
  const int ti = bid - 2048;
  const float* in;
  unsigned short* dst;
  int R, C, bx, by;
  if (ti < 6144) {
    const int z = ti / 2048, within = ti % 2048;
    in = (z == 0) ? Wq : (z == 1) ? Wk : Wv;
    dst = Wcat + (size_t)z * 4096 * 512;
    R = 512; C = 4096; bx = within % 128; by = within / 128;
  } else {
    const int t2 = ti - 6144;
    in = Wu; dst = Wut;
    R = 4096; C = 512; bx = t2 % 16; by = t2 / 16;
  }
  const int c0 = bx * 32, r0 = by * 32;
  #pragma unroll
  for (int i = ty; i < 32; i += 8)
    tile[i][tx] = in[(size_t)(r0 + i) * C + (c0 + tx)];
  __syncthreads();
  #pragma unroll
  for (int i = ty; i < 32; i += 8)
    dst[(size_t)(c0 + i) * R + (r0 + tx)] = f2bu(tile[tx][i]);
}

// ---------------- fused QKV projection v3b (round-17, unchanged) ----------------
__global__ __launch_bounds__(512, 1)
void gemm_qkv(const unsigned short* __restrict__ A,
              const unsigned short* __restrict__ B,
              unsigned short* __restrict__ Qo,
              unsigned short* __restrict__ Ko,
              unsigned short* __restrict__ Vo) {
  __shared__ __align__(16) char smem[131072];  // Abuf[2]:0,32K  Bbuf[2]:64K,96K
  const int tid = threadIdx.x, lane = tid & 63, w = tid >> 6;
  const int wm = w >> 2, wn = w & 3;
  const int bid = blockIdx.x;
  const int x = bid & 7, inner = bid >> 3;     // grid = 192*NB (%8==0)
  const int p0 = (x * 6 + inner % 6) * 256;    // n-tile strip per XCD
  const int p1 = (inner / 6) * 256;            // m-tile

  f32x4 acc[8][4];
  #pragma unroll
  for (int i = 0; i < 8; ++i)
    #pragma unroll
    for (int j = 0; j < 4; ++j)
      acc[i][j] = f32x4{0.f, 0.f, 0.f, 0.f};

  auto stage = [&](int t, int c) {           // 8 gload_lds / thread
    const int kt = t * 128;
    #pragma unroll
    for (int is = 0; is < 4; ++is) {
      const int ob = is * 8192 + w * 1024;
      const int ol = ob + lane * 16;
      const int row = ol >> 7, bo = ol & 127;
      const int sw = (row & 7) << 4;
      GLOAD_LDS16((const char*)A + (size_t)(p0 + row) * 1024 + kt + (bo ^ sw),
                  smem + c * 32768 + ob);
      GLOAD_LDS16((const char*)B + (size_t)(p1 + row) * 1024 + kt + (bo ^ sw),
                  smem + 65536 + c * 32768 + ob);
    }
  };

  stage(0, 0);
  stage(1, 1);
  asm volatile("s_waitcnt vmcnt(8)" ::: "memory");
  __builtin_amdgcn_sched_barrier(0);
  __builtin_amdgcn_s_barrier();

  for (int t = 0; t < 8; ++t) {
    const int c = t & 1;
    const char* Ab = smem + c * 32768;
    const char* Bb = smem + 65536 + c * 32768;
    #pragma unroll
    for (int ks = 0; ks < 2; ++ks) {
      bf16x8 af[8], bf[4];
      #pragma unroll
      for (int mi = 0; mi < 8; ++mi) {
        const int row = wm * 128 + mi * 16 + (lane & 15);
        af[mi] = *reinterpret_cast<const bf16x8*>(
            Ab + row * 128 + ((ks * 64 + ((lane >> 4) << 4)) ^ ((row & 7) << 4)));
      }
      #pragma unroll
      for (int ni = 0; ni < 4; ++ni) {
        const int row = wn * 64 + ni * 16 + (lane & 15);
        bf[ni] = *reinterpret_cast<const bf16x8*>(
            Bb + row * 128 + ((ks * 64 + ((lane >> 4) << 4)) ^ ((row & 7) << 4)));
      }
      #pragma unroll
      for (int mi = 0; mi < 8; ++mi)
        #pragma unroll
        for (int ni = 0; ni < 4; ++ni)
          acc[mi][ni] = __builtin_amdgcn_mfma_f32_16x16x32_bf16(af[mi], bf[ni], acc[mi][ni], 0, 0, 0);
    }
    asm volatile("" ::: "memory");
    __builtin_amdgcn_sched_barrier(0);
    __builtin_amdgcn_s_barrier();
    if (t + 2 < 8) stage(t + 2, c);
    if (t + 1 < 8) {
      if (t + 2 < 8) asm volatile("s_waitcnt vmcnt(8)" ::: "memory");
      else           asm volatile("s_waitcnt vmcnt(0)" ::: "memory");
      __builtin_amdgcn_sched_barrier(0);
      __builtin_amdgcn_s_barrier();
    }
  }

  const int region = p0 >> 12;
  if (region < 2) {
    const float qs = (region == 0) ? QK_SCALE_LOG2E : QK_SCALE;
    unsigned short* dst = (region == 0) ? Qo : Ko;
    unsigned short* Tl = reinterpret_cast<unsigned short*>(smem);  // [256 t][256 d]
    #pragma unroll
    for (int mi = 0; mi < 8; ++mi) {
      #pragma unroll
      for (int ni = 0; ni < 4; ++ni) {
        const int dl0 = wm * 128 + mi * 16 + ((lane >> 4) << 2);
        const int tl = wn * 64 + ni * 16 + (lane & 15);
        ushort4 u;
        u.x = f2bu(acc[mi][ni][0] * qs); u.y = f2bu(acc[mi][ni][1] * qs);
        u.z = f2bu(acc[mi][ni][2] * qs); u.w = f2bu(acc[mi][ni][3] * qs);
        *reinterpret_cast<ushort4*>((char*)Tl + (size_t)tl * 512 + ((dl0 * 2) ^ ((tl & 7) << 4))) = u;
      }
    }
    __syncthreads();
    const int bb = p1 >> 10, t0 = p1 & 1023;
    const int hh = (p0 & 4095) >> 9, d0 = p0 & 511;
    unsigned short* qdst = dst + ((size_t)(bb * NH + hh) * T_SEQ + t0) * DH + d0;
    #pragma unroll
    for (int i = 0; i < 16; ++i) {
      const int idx = i * 512 + tid;
      const int tr = idx >> 5, dc = (idx & 31) * 16;
      *reinterpret_cast<uint4*>((char*)qdst + (size_t)tr * DH * 2 + dc) =
          *reinterpret_cast<const uint4*>((char*)Tl + (size_t)tr * 512 + (dc ^ ((tr & 7) << 4)));
    }
  } else {
    unsigned short* Vl = reinterpret_cast<unsigned short*>(smem);  // [256 d][256 t]
    #pragma unroll
    for (int mi = 0; mi < 8; ++mi) {
      #pragma unroll
      for (int ni = 0; ni < 4; ++ni) {
        const int dl0 = wm * 128 + mi * 16 + ((lane >> 4) << 2);
        const int tl = wn * 64 + ni * 16 + (lane & 15);
        #pragma unroll
        for (int r = 0; r < 4; ++r) {
          const int dl = dl0 + r;
          Vl[dl * 256 + (tl ^ ((dl & 7) << 3))] = f2bu(acc[mi][ni][r]);
        }
      }
    }
    __syncthreads();
    const int bb = p1 >> 10, t0 = p1 & 1023;
    const int hh = (p0 - 8192) >> 9, d0 = (p0 - 8192) & 511;
    unsigned short* vdst = Vo + ((size_t)(bb * NH + hh) * DH + d0) * T_SEQ + t0;
    #pragma unroll
    for (int i = 0; i < 16; ++i) {
      const int idx = i * 512 + tid;
      const int dr = idx >> 5, tc = (idx & 31) * 8;
      *reinterpret_cast<uint4*>(vdst + (size_t)dr * T_SEQ + tc) =
          *reinterpret_cast<const uint4*>(Vl + dr * 256 + (tc ^ ((dr & 7) << 3)));
    }
  }
}

// ---------------- output GEMM v2 (round-10, unchanged) ----------------
__global__ __launch_bounds__(256, 4)
void gemm_out(const unsigned short* __restrict__ A,   // Wut [512][4096]
              const unsigned short* __restrict__ B,   // Ob  [NB*1024][4096]
              const float* __restrict__ bias,
              float* __restrict__ C) {
  __shared__ __align__(16) char As[8192];
  __shared__ __align__(16) char Bs[16384];
  const int tid = threadIdx.x, lane = tid & 63, w = tid >> 6;
  const int bid = blockIdx.x;
  const int x = bid & 7, inner = bid >> 3;
  const int mtiles_per_xcd = gridDim.x >> 7;
  const int c0 = (inner & 15) * 32;
  const int m0 = (x * mtiles_per_xcd + (inner >> 4)) * 64;
  const int Kd = HK;

  f32x4 acc[2];
  acc[0] = f32x4{0.f, 0.f, 0.f, 0.f};
  acc[1] = f32x4{0.f, 0.f, 0.f, 0.f};

  for (int kt = 0; kt < Kd; kt += 128) {
    __syncthreads();
    #pragma unroll
    for (int is = 0; is < 2; ++is) {
      const int ob = is * 4096 + w * 1024;
      const int ol = ob + lane * 16;
      const int row = ol >> 8, bo = ol & 255;
      GLOAD_LDS16((const char*)A + ((size_t)(c0 + row) * Kd + kt) * 2 + (bo ^ ((row & 15) << 4)), As + ob);
    }
    #pragma unroll
    for (int is = 0; is < 4; ++is) {
      const int ob = is * 4096 + w * 1024;
      const int ol = ob + lane * 16;
      const int row = ol >> 8, bo = ol & 255;
      GLOAD_LDS16((const char*)B + ((size_t)(m0 + row) * Kd + kt) * 2 + (bo ^ ((row & 15) << 4)), Bs + ob);
    }
    __syncthreads();
    #pragma unroll
    for (int ks = 0; ks < 4; ++ks) {
      const int ko = ks * 64 + ((lane >> 4) << 4);
      bf16x8 af0, af1, bf;
      { const int row = (lane & 15);
        af0 = *reinterpret_cast<const bf16x8*>(As + row * 256 + (ko ^ ((row & 15) << 4))); }
      { const int row = 16 + (lane & 15);
        af1 = *reinterpret_cast<const bf16x8*>(As + row * 256 + (ko ^ ((row & 15) << 4))); }
      { const int row = w * 16 + (lane & 15);
        bf = *reinterpret_cast<const bf16x8*>(Bs + row * 256 + (ko ^ ((row & 15) << 4))); }
      acc[0] = __builtin_amdgcn_mfma_f32_16x16x32_bf16(af0, bf, acc[0], 0, 0, 0);
      acc[1] = __builtin_amdgcn_mfma_f32_16x16x32_bf16(af1, bf, acc[1], 0, 0, 0);
    }
  }

  const int m = m0 + w * 16 + (lane & 15);
  #pragma unroll
  for (int fc = 0; fc < 2; ++fc) {
    const int c = c0 + fc * 16 + ((lane >> 4) << 2);
    const float4 bn = *reinterpret_cast<const float4*>(&bias[c]);
    float4 v;
    v.x = acc[fc][0] + bn.x; v.y = acc[fc][1] + bn.y;
    v.z = acc[fc][2] + bn.z; v.w = acc[fc][3] + bn.w;
    *reinterpret_cast<float4*>(&C[(size_t)m * DH + c]) = v;
  }
}

// ---------------- flash attention v4c (round-17, unchanged) ----------------
__global__ __launch_bounds__(512, 1)
void attn_kernel(const unsigned short* __restrict__ Qg,
                 const unsigned short* __restrict__ Kg,
                 const unsigned short* __restrict__ Vtg,
                 unsigned short* __restrict__ Og) {
  __shared__ __align__(16) char Ks[2][32768];      // 32 x 512 bf16, row-swz (row&7)<<4
  __shared__ __align__(16) char Vts[2][32768];     // 512 x 32 bf16, row-swz (row&3)<<4
  __shared__ float S_lds[64 * 32];                 // stride 32 + col^((row&7)<<2)
  __shared__ __align__(16) char P_lds[64 * 64];    // 64 x 32 bf16, swz (r&3)<<4
  __shared__ float Mrow[64], Lrow[64], Arow[64];
  __shared__ int rflag;

  const int tid = threadIdx.x, lane = tid & 63, w = tid >> 6;
  const int n = blockIdx.x;
  const int h = n & 7, p = (n >> 3) & 7, b = n >> 6;
  const int bh = b * NH + h;

  const unsigned short* Qbase = Qg + (size_t)bh * T_SEQ * DH;
  const char* Kbase = (const char*)(Kg + (size_t)bh * T_SEQ * DH);   // t-row stride 1024 B
  const char* Vbase = (const char*)(Vtg + (size_t)bh * DH * T_SEQ);  // d-row stride 2048 B

  auto stage = [&](int st, int buf) {
    #pragma unroll
    for (int is = 0; is < 4; ++is) {
      const int ob = is * 8192 + w * 1024;
      const int ol = ob + lane * 16;
      { const int row = ol >> 10, bo = ol & 1023;
        GLOAD_LDS16(Kbase + (size_t)(st * 32 + row) * 1024 + (bo ^ ((row & 7) << 4)), Ks[buf] + ob); }
      { const int row = ol >> 6, bo = ol & 63;
        GLOAD_LDS16(Vbase + (size_t)row * 2048 + st * 64 + (bo ^ ((row & 3) << 4)), Vts[buf] + ob); }
    }
  };

  for (int rep = 0; rep < 2; ++rep) {
    const int qt = rep ? 15 - p : p;
    const int nst = 2 * qt + 2;
    __syncthreads();  // guard stats/LDS from previous rep

    bf16x8 qreg[16];
    {
      const int qrow = qt * 64 + ((w >> 1) << 4) + (lane & 15);
      const unsigned short* qp = Qbase + (size_t)qrow * DH + ((lane >> 4) << 3);
      #pragma unroll
      for (int k2 = 0; k2 < 16; ++k2)
        qreg[k2] = *reinterpret_cast<const bf16x8*>(qp + k2 * 32);
    }

    f32x4 o[2][8];
    #pragma unroll
    for (int mi = 0; mi < 2; ++mi)
      #pragma unroll
      for (int ni = 0; ni < 8; ++ni)
        o[mi][ni] = f32x4{0.f, 0.f, 0.f, 0.f};

    if (tid < 64) { Mrow[tid] = -INFINITY; Lrow[tid] = 0.f; }

    int cur = 0;
    stage(0, 0);

    for (int st = 0; st < nst; ++st) {
      __syncthreads();  // implicit vmcnt(0): stage(st) complete + all LDS quiesced
      if (st + 1 < nst) stage(st + 1, cur ^ 1);  // in flight across raw barriers below
      if (tid == 0) rflag = 0;

      // ---- QK: wave w computes S fragment (w>>1, w&1); 2 independent partials ----
      {
        const int krow = ((w & 1) << 4) + (lane & 15);
        const char* kr = Ks[cur] + krow * 1024;
        const int sw = (krow & 7) << 4;
        f32x4 sA = f32x4{0.f, 0.f, 0.f, 0.f};
        f32x4 sB = f32x4{0.f, 0.f, 0.f, 0.f};
        __builtin_amdgcn_s_setprio(1);
        #pragma unroll
        for (int ks = 0; ks < 16; ks += 2) {
          bf16x8 kf0 = *reinterpret_cast<const bf16x8*>(kr + ((ks * 64 + ((lane >> 4) << 4)) ^ sw));
          bf16x8 kf1 = *reinterpret_cast<const bf16x8*>(kr + (((ks + 1) * 64 + ((lane >> 4) << 4)) ^ sw));
          sA = __builtin_amdgcn_mfma_f32_16x16x32_bf16(qreg[ks], kf0, sA, 0, 0, 0);
          sB = __builtin_amdgcn_mfma_f32_16x16x32_bf16(qreg[ks + 1], kf1, sB, 0, 0, 0);
        }
        __builtin_amdgcn_s_setprio(0);
        const f32x4 s = sA + sB;
        const int col = ((w & 1) << 4) + (lane & 15);
        const int rbase = ((w >> 1) << 4) + ((lane >> 4) << 2);
        #pragma unroll
        for (int r = 0; r < 4; ++r)
          S_lds[(rbase + r) * 32 + (col ^ (((rbase + r) & 7) << 2))] = s[r];
      }
      asm volatile("s_waitcnt lgkmcnt(0)" ::: "memory");
      __builtin_amdgcn_sched_barrier(0);
      __builtin_amdgcn_s_barrier();   // raw: staged loads stay in flight

      // ---- online softmax (log2 domain): 8 threads per row, 64 rows ----
      {
        const int r = tid >> 3, cg = tid & 7;
        const int grow = qt * 64 + r;
        const int base = r * 32 + ((cg * 4) ^ ((r & 7) << 2));
        float sv[4];
        #pragma unroll
        for (int j = 0; j < 4; ++j) {
          const int c = cg * 4 + j;
          const float x = S_lds[base + j];
          sv[j] = (st * 32 + c > grow) ? -INFINITY : x;
        }
        float pm = fmaxf(fmaxf(sv[0], sv[1]), fmaxf(sv[2], sv[3]));
        pm = fmaxf(pm, __shfl_xor(pm, 1));
        pm = fmaxf(pm, __shfl_xor(pm, 2));
        pm = fmaxf(pm, __shfl_xor(pm, 4));
        const float m_old = Mrow[r];
        const bool defer = (pm <= m_old + 11.0f);   // T13
        const float m_new = defer ? m_old : pm;
        float ps;
        ushort4 pu;
        { float p0 = exp2f(sv[0] - m_new), p1 = exp2f(sv[1] - m_new),
                p2 = exp2f(sv[2] - m_new), p3 = exp2f(sv[3] - m_new);
          ps = p0 + p1 + p2 + p3;
          pu.x = f2bu(p0); pu.y = f2bu(p1); pu.z = f2bu(p2); pu.w = f2bu(p3); }
        *reinterpret_cast<ushort4*>(P_lds + r * 64 + ((cg * 8) ^ ((r & 3) << 4))) = pu;
        ps += __shfl_xor(ps, 1);
        ps += __shfl_xor(ps, 2);
        ps += __shfl_xor(ps, 4);
        if (cg == 0) {
          const float alpha = defer ? 1.0f : exp2f(m_old - m_new);
          if (!defer) { rflag = 1; Mrow[r] = m_new; }
          Arow[r] = alpha;
          Lrow[r] = alpha * Lrow[r] + ps;
        }
      }
      asm volatile("s_waitcnt lgkmcnt(0)" ::: "memory");
      __builtin_amdgcn_sched_barrier(0);
      __builtin_amdgcn_s_barrier();   // raw

      // ---- PV: wave w -> O rows 32*(w>>2)+, cols 128*(w&3)+ ----
      {
        bf16x8 pf[2];
        #pragma unroll
        for (int mi = 0; mi < 2; ++mi) {
          const int pr = ((w >> 2) << 5) + mi * 16 + (lane & 15);
          pf[mi] = *reinterpret_cast<const bf16x8*>(
              P_lds + pr * 64 + ((((lane >> 4) << 4)) ^ ((pr & 3) << 4)));
        }
        if (rflag) {  // skip O-rescale when no row rescaled this step
          #pragma unroll
          for (int mi = 0; mi < 2; ++mi) {
            const int rb = ((w >> 2) << 5) + mi * 16 + ((lane >> 4) << 2);
            const f32x4 al = f32x4{Arow[rb], Arow[rb + 1], Arow[rb + 2], Arow[rb + 3]};
            #pragma unroll
            for (int ni = 0; ni < 8; ++ni) o[mi][ni] *= al;
          }
        }
        __builtin_amdgcn_s_setprio(1);
        #pragma unroll
        for (int ni = 0; ni < 8; ++ni) {
          const int vr = ((w & 3) << 7) + ni * 16 + (lane & 15);
          bf16x8 vf = *reinterpret_cast<const bf16x8*>(
              Vts[cur] + vr * 64 + ((((lane >> 4) << 4)) ^ ((vr & 3) << 4)));
          o[0][ni] = __builtin_amdgcn_mfma_f32_16x16x32_bf16(pf[0], vf, o[0][ni], 0, 0, 0);
          o[1][ni] = __builtin_amdgcn_mfma_f32_16x16x32_bf16(pf[1], vf, o[1][ni], 0, 0, 0);
        }
        __builtin_amdgcn_s_setprio(0);
      }
      cur ^= 1;
    }

    // normalize and store (O layout (b,t,h,d))
    #pragma unroll
    for (int mi = 0; mi < 2; ++mi) {
      const int rb = ((w >> 2) << 5) + mi * 16 + ((lane >> 4) << 2);
      f32x4 li;
      #pragma unroll
      for (int r = 0; r < 4; ++r) li[r] = 1.f / Lrow[rb + r];
      #pragma unroll
      for (int ni = 0; ni < 8; ++ni) {
        const int d = ((w & 3) << 7) + ni * 16 + (lane & 15);
        const size_t base = ((size_t)(b * T_SEQ + qt * 64 + rb) * NH + h) * DH + d;
        #pragma unroll
        for (int r = 0; r < 4; ++r)
          Og[base + (size_t)r * NH * DH] = f2bu(o[mi][ni][r] * li[r]);
      }
    }
  }
}

// ---------------- host launch (adaptive workspace chunking) ----------------
extern "C" void kernel_launch(void* const* d_in, const int* in_sizes, int n_in,
                              void* d_out, int out_size, void* d_ws, size_t ws_size,
                              hipStream_t stream) {
  (void)in_sizes; (void)n_in; (void)out_size;
  const float* x  = (const float*)d_in[0];
  const float* Wq = (const float*)d_in[1];
  const float* Wk = (const float*)d_in[2];
  const float* Wv = (const float*)d_in[3];
  const float* Wu = (const float*)d_in[4];
  const float* bu = (const float*)d_in[5];
  float* out = (float*)d_out;

  const size_t PERS = (size_t)8192 * 512 * 2 + 3 * (size_t)4096 * 512 * 2 + (size_t)512 * 4096 * 2;
  int NB = 8;
  while (NB > 1 && PERS + 4 * ((size_t)NB * 1024 * 4096 * 2) + 65536 > ws_size) NB >>= 1;

  size_t off = 0;
  auto wsp = [&](size_t bytes) {
    char* p = (char*)d_ws + off;
    off += (bytes + 255) & ~(size_t)255;
    return p;
  };
  unsigned short* xb   = (unsigned short*)wsp((size_t)8192 * 512 * 2);
  unsigned short* Wcat = (unsigned short*)wsp(3 * (size_t)4096 * 512 * 2);  // Wq^T|Wk^T|Wv^T
  unsigned short* Wut  = (unsigned short*)wsp((size_t)512 * 4096 * 2);
  const size_t CHB = (size_t)NB * 1024 * 4096 * 2;
  unsigned short* Qc = (unsigned short*)wsp(CHB);
  unsigned short* Kc = (unsigned short*)wsp(CHB);
  unsigned short* Vc = (unsigned short*)wsp(CHB);
  unsigned short* Oc = (unsigned short*)wsp(CHB);

  preamble_kernel<<<10240, 256, 0, stream>>>(x, Wq, Wk, Wv, Wu, xb, Wcat, Wut);

  const int nchunks = 8 / NB;
  for (int c = 0; c < nchunks; ++c) {
    const unsigned short* xc = xb + (size_t)c * NB * 1024 * 512;
    gemm_qkv<<<192 * NB, 512, 0, stream>>>(Wcat, xc, Qc, Kc, Vc);
    attn_kernel<<<64 * NB, 512, 0, stream>>>(Qc, Kc, Vc, Oc);
    gemm_out<<<256 * NB, 256, 0, stream>>>(Wut, Oc, bu, out + (size_t)c * NB * 1024 * 512);
  }
}